// Round 4
// baseline (509.410 us; speedup 1.0000x reference)
//
#include <hip/hip_runtime.h>
#include <hip/hip_bf16.h>
#include <stdint.h>

// Problem constants (from reference):
// x: [1,4,72,72,72] fp32 -> x4: [4,72,5184]
// attentions: [1,4,4608,4608] fp32
// P=9, nH=8, nW=576, L=4608, P*P=81
#define PSZ    9
#define CH     4
#define LROWS  4608   // L (also the GEMM K dim)
#define NWp    576
#define HPdim  72
#define WPdim  5184
#define NPAD   96     // 81 padded to 6 tiles of 16
#define NVALID 81
#define KSPLIT 4
#define KSEG   (LROWS / KSPLIT)   // 1152
#define KBLK   32                 // k per B chunk
#define NKB    (LROWS / KBLK)     // 144
#define BCH    (NPAD * KBLK)      // 3072 elements per (kb) B chunk

typedef short s16x8 __attribute__((ext_vector_type(8)));
typedef float f32x4 __attribute__((ext_vector_type(4)));

__device__ __forceinline__ uint16_t f2bf(float f) {
    uint32_t u = __builtin_bit_cast(uint32_t, f);
    u += 0x8000u;
    return (uint16_t)(u >> 16);
}

// Packed fp32x8 -> bf16x8 fragment (v_cvt_pk_bf16_f32, RNE)
__device__ __forceinline__ s16x8 cvt8(float4 a, float4 b) {
    union { s16x8 v; uint32_t u[4]; } r;
    __hip_bfloat162 h0 = __float22bfloat162_rn(make_float2(a.x, a.y));
    __hip_bfloat162 h1 = __float22bfloat162_rn(make_float2(a.z, a.w));
    __hip_bfloat162 h2 = __float22bfloat162_rn(make_float2(b.x, b.y));
    __hip_bfloat162 h3 = __float22bfloat162_rn(make_float2(b.z, b.w));
    __builtin_memcpy(&r.u[0], &h0, 4);
    __builtin_memcpy(&r.u[1], &h1, 4);
    __builtin_memcpy(&r.u[2], &h2, 4);
    __builtin_memcpy(&r.u[3], &h3, 4);
    return r.v;
}

__device__ __forceinline__ int count8(float4 a, float4 b) {
    return (a.x != 0.f) + (a.y != 0.f) + (a.z != 0.f) + (a.w != 0.f)
         + (b.x != 0.f) + (b.y != 0.f) + (b.z != 0.f) + (b.w != 0.f);
}

// Kernel 1: build patches bf16 in layout pb[c][kb][n(96)][ks(32)].
// pb[((c*144+kb)*96+n)*32+ks] = bf16(patches[c][n][m=kb*32+ks]),
// patches[c, n=ki*9+kj, m=bi*576+bj] = x4[c, bi*9+ki, bj*9+kj].
__global__ __launch_bounds__(256) void build_pb_kernel(
    const float* __restrict__ x, uint16_t* __restrict__ pb)
{
    __shared__ float xs[PSZ][288];
    const int blk = blockIdx.x;            // 0..575
    const int c   = blk / NKB;
    const int kb  = blk - c * NKB;
    const int bi  = kb / 18;
    const int bj0 = (kb - bi * 18) * KBLK;

    const float* src = x + (size_t)(c * HPdim + bi * PSZ) * WPdim + bj0 * PSZ;
    for (int idx = threadIdx.x; idx < PSZ * 288; idx += 256) {
        int r = idx / 288, col = idx - r * 288;
        xs[r][col] = src[(size_t)r * WPdim + col];
    }
    __syncthreads();

    uint16_t* dst = pb + (size_t)(c * NKB + kb) * BCH;
    for (int oidx = threadIdx.x; oidx < BCH; oidx += 256) {
        int n = oidx / KBLK, ks = oidx - n * KBLK;
        uint16_t v = 0;
        if (n < NVALID) {
            int ki = n / PSZ, kj = n - ki * PSZ;
            v = f2bf(xs[ki][ks * PSZ + kj]);
        }
        dst[oidx] = v;
    }
}

// Kernel 2 (v5): one block per 64(l) x 96(n) tile; 4 waves K-split (1152 each).
// Four 16-row accumulator sets share every B fragment -> B-side L2 traffic
// quarters vs v3 (1.0 GB -> 0.25 GB); per-XCD L2 occupancy drops below the
// HBM floor. Grid = 288 blocks (8 XCD-slots x 36).
//  - KEPT: XCD-pinned channel mapping, register ping-pong, peeled last iter.
//  - Epilogue: two LDS passes (39 KB not 78 KB -> 2 blocks/CU), work spread
//    over 4 waves (wave s epilogues row-group s).
__global__ __launch_bounds__(256, 2) void cross_gemm_kernel(
    const float* __restrict__ x,
    const float* __restrict__ attn,
    const uint16_t* __restrict__ pb,
    float* __restrict__ out)
{
    __shared__ float red[2][KSPLIT - 1][64][26];
    __shared__ int   cshared[4][KSPLIT][16];

    const int lane = threadIdx.x & 63;
    const int widx = threadIdx.x >> 6;
    const int blk  = blockIdx.x;              // 0..287
    // XCD-pinned decomposition: 288 = 8 slots x 36
    const int slot = blk & 7;                 // measured HW round-robin -> XCD id
    const int ii   = blk >> 3;                // 0..35
    const int c    = slot >> 1;               // one channel per XCD-pair
    const int tile = (slot & 1) * 36 + ii;    // 0..71 (64-row tiles)
    const int r0   = tile * 64;
    const int li   = lane & 15;
    const int quad = lane >> 4;
    const int k0   = widx * KSEG;
    const int kb0  = k0 / KBLK;               // widx*36

    const float* ap[4];
#pragma unroll
    for (int g = 0; g < 4; ++g)
        ap[g] = attn + (size_t)(c * LROWS + r0 + g * 16 + li) * LROWS + k0 + quad * 8;
    const uint16_t* bp = pb + (size_t)(c * NKB + kb0) * BCH + li * KBLK + quad * 8;

    f32x4 acc[4][6];
#pragma unroll
    for (int g = 0; g < 4; ++g)
#pragma unroll
        for (int t = 0; t < 6; ++t) acc[g][t] = (f32x4){0.f, 0.f, 0.f, 0.f};

    int cnt[4] = {0, 0, 0, 0};
    const int DITERS = KSEG / 64;   // 18

    // preload set0 (k = 0): four row-groups x 8 floats
    float4 a0[4][2];
#pragma unroll
    for (int g = 0; g < 4; ++g) {
        a0[g][0] = *(const float4*)(ap[g]);
        a0[g][1] = *(const float4*)(ap[g] + 4);
    }
    s16x8 b0[6];
#pragma unroll
    for (int t = 0; t < 6; ++t) b0[t] = *(const s16x8*)(bp + t * 16 * KBLK);

    for (int dit = 0; dit < DITERS - 1; ++dit) {
        // issue set1 loads (k = 64*dit + 32) -- always in-segment
        float4 a1[4][2];
#pragma unroll
        for (int g = 0; g < 4; ++g) {
            a1[g][0] = *(const float4*)(ap[g] + 32);
            a1[g][1] = *(const float4*)(ap[g] + 36);
        }
        s16x8 b1[6];
#pragma unroll
        for (int t = 0; t < 6; ++t) b1[t] = *(const s16x8*)(bp + BCH + t * 16 * KBLK);

        // compute set0 (all four row-groups share b0)
#pragma unroll
        for (int g = 0; g < 4; ++g) {
            cnt[g] += count8(a0[g][0], a0[g][1]);
            s16x8 af = cvt8(a0[g][0], a0[g][1]);
#pragma unroll
            for (int t = 0; t < 6; ++t)
                acc[g][t] = __builtin_amdgcn_mfma_f32_16x16x32_bf16(af, b0[t], acc[g][t], 0, 0, 0);
        }

        // advance; issue set0 loads for next trip
#pragma unroll
        for (int g = 0; g < 4; ++g) ap[g] += 64;
        bp += 2 * BCH;
#pragma unroll
        for (int g = 0; g < 4; ++g) {
            a0[g][0] = *(const float4*)(ap[g]);
            a0[g][1] = *(const float4*)(ap[g] + 4);
        }
#pragma unroll
        for (int t = 0; t < 6; ++t) b0[t] = *(const s16x8*)(bp + t * 16 * KBLK);

        // compute set1
#pragma unroll
        for (int g = 0; g < 4; ++g) {
            cnt[g] += count8(a1[g][0], a1[g][1]);
            s16x8 af = cvt8(a1[g][0], a1[g][1]);
#pragma unroll
            for (int t = 0; t < 6; ++t)
                acc[g][t] = __builtin_amdgcn_mfma_f32_16x16x32_bf16(af, b1[t], acc[g][t], 0, 0, 0);
        }
    }

    // peeled final iteration (no next-trip loads)
    {
        float4 a1[4][2];
#pragma unroll
        for (int g = 0; g < 4; ++g) {
            a1[g][0] = *(const float4*)(ap[g] + 32);
            a1[g][1] = *(const float4*)(ap[g] + 36);
        }
        s16x8 b1[6];
#pragma unroll
        for (int t = 0; t < 6; ++t) b1[t] = *(const s16x8*)(bp + BCH + t * 16 * KBLK);

#pragma unroll
        for (int g = 0; g < 4; ++g) {
            cnt[g] += count8(a0[g][0], a0[g][1]);
            s16x8 af = cvt8(a0[g][0], a0[g][1]);
#pragma unroll
            for (int t = 0; t < 6; ++t)
                acc[g][t] = __builtin_amdgcn_mfma_f32_16x16x32_bf16(af, b0[t], acc[g][t], 0, 0, 0);
        }
#pragma unroll
        for (int g = 0; g < 4; ++g) {
            cnt[g] += count8(a1[g][0], a1[g][1]);
            s16x8 af = cvt8(a1[g][0], a1[g][1]);
#pragma unroll
            for (int t = 0; t < 6; ++t)
                acc[g][t] = __builtin_amdgcn_mfma_f32_16x16x32_bf16(af, b1[t], acc[g][t], 0, 0, 0);
        }
    }

    // Per-wave nonzero reduction per row-group:
    // row partials live in lanes i, i+16, i+32, i+48
#pragma unroll
    for (int g = 0; g < 4; ++g) {
        cnt[g] += __shfl_down(cnt[g], 32);
        cnt[g] += __shfl_down(cnt[g], 16);
    }
    if (lane < 16) {
#pragma unroll
        for (int g = 0; g < 4; ++g) cshared[g][widx][lane] = cnt[g];
    }

    // Two-pass cross-wave reduction + epilogue.
    // Pass p handles sets s0=2p, s1=2p+1; wave s epilogues set s.
#pragma unroll
    for (int p = 0; p < 2; ++p) {
        const int s0 = 2 * p, s1 = 2 * p + 1;
        if (p) __syncthreads();   // pass-0 reads done before overwrite

        if (widx != s0) {
            const int j = widx - (widx > s0 ? 1 : 0);
#pragma unroll
            for (int t = 0; t < 6; ++t)
#pragma unroll
                for (int r = 0; r < 4; ++r)
                    red[0][j][lane][t * 4 + r] = acc[s0][t][r];
        }
        if (widx != s1) {
            const int j = widx - (widx > s1 ? 1 : 0);
#pragma unroll
            for (int t = 0; t < 6; ++t)
#pragma unroll
                for (int r = 0; r < 4; ++r)
                    red[1][j][lane][t * 4 + r] = acc[s1][t][r];
        }
        __syncthreads();

        // epilogue: C/D layout col = lane&15 (n), row = quad*4 + reg (l)
#pragma unroll
        for (int h = 0; h < 2; ++h) {
            const int s = 2 * p + h;
            if (widx == s) {
#pragma unroll
                for (int reg = 0; reg < 4; ++reg) {
                    const int lrow = quad * 4 + reg;
                    const int cnt_r = cshared[s][0][lrow] + cshared[s][1][lrow]
                                    + cshared[s][2][lrow] + cshared[s][3][lrow];
                    const float scale = 1.0f / ((float)cnt_r + 1e-5f);
                    const int l  = r0 + s * 16 + lrow;
                    const int bi = l / NWp;
                    const int bj = l - bi * NWp;
#pragma unroll
                    for (int t = 0; t < 6; ++t) {
                        const int n = t * 16 + li;
                        if (n < NVALID) {
                            const float v = acc[s][t][reg]
                                          + red[h][0][lane][t * 4 + reg]
                                          + red[h][1][lane][t * 4 + reg]
                                          + red[h][2][lane][t * 4 + reg];
                            const int ki = n / PSZ, kj = n - (n / PSZ) * PSZ;
                            const size_t idx = (size_t)(c * HPdim + bi * PSZ + ki) * WPdim
                                             + (size_t)(bj * PSZ + kj);
                            const float xv = x[idx];
                            const float o  = xv * (1.0f + v * scale);
                            out[idx] = (o > 0.f) ? o : 0.2f * o;
                        }
                    }
                }
            }
        }
    }
}

extern "C" void kernel_launch(void* const* d_in, const int* in_sizes, int n_in,
                              void* d_out, int out_size, void* d_ws, size_t ws_size,
                              hipStream_t stream)
{
    const float* x    = (const float*)d_in[0];
    const float* attn = (const float*)d_in[1];
    float* out        = (float*)d_out;
    uint16_t* pb      = (uint16_t*)d_ws;   // CH*NKB*BCH bf16 = 3.5 MB

    build_pb_kernel<<<CH * NKB, 256, 0, stream>>>(x, pb);
    cross_gemm_kernel<<<CH * 72, 256, 0, stream>>>(x, attn, pb, out);
}

// Round 5
// 494.173 us; speedup vs baseline: 1.0308x; 1.0308x over previous
//
#include <hip/hip_runtime.h>
#include <hip/hip_bf16.h>
#include <stdint.h>

// Problem constants (from reference):
// x: [1,4,72,72,72] fp32 -> x4: [4,72,5184]
// attentions: [1,4,4608,4608] fp32
// P=9, nH=8, nW=576, L=4608, P*P=81
#define PSZ    9
#define CH     4
#define LROWS  4608   // L (also the GEMM K dim)
#define NWp    576
#define HPdim  72
#define WPdim  5184
#define NPAD   96     // 81 padded to 6 tiles of 16
#define NVALID 81
#define KSPLIT 4
#define KSEG   (LROWS / KSPLIT)   // 1152
#define KBLK   32                 // k per B chunk
#define NKB    (LROWS / KBLK)     // 144
#define BCH    (NPAD * KBLK)      // 3072 elements per (kb) B chunk

typedef short s16x8 __attribute__((ext_vector_type(8)));
typedef float f32x4 __attribute__((ext_vector_type(4)));

__device__ __forceinline__ uint16_t f2bf(float f) {
    uint32_t u = __builtin_bit_cast(uint32_t, f);
    u += 0x8000u;
    return (uint16_t)(u >> 16);
}

// Packed fp32x8 -> bf16x8 fragment (v_cvt_pk_bf16_f32, RNE)
__device__ __forceinline__ s16x8 cvt8(float4 a, float4 b) {
    union { s16x8 v; uint32_t u[4]; } r;
    __hip_bfloat162 h0 = __float22bfloat162_rn(make_float2(a.x, a.y));
    __hip_bfloat162 h1 = __float22bfloat162_rn(make_float2(a.z, a.w));
    __hip_bfloat162 h2 = __float22bfloat162_rn(make_float2(b.x, b.y));
    __hip_bfloat162 h3 = __float22bfloat162_rn(make_float2(b.z, b.w));
    __builtin_memcpy(&r.u[0], &h0, 4);
    __builtin_memcpy(&r.u[1], &h1, 4);
    __builtin_memcpy(&r.u[2], &h2, 4);
    __builtin_memcpy(&r.u[3], &h3, 4);
    return r.v;
}

__device__ __forceinline__ int count8(float4 a, float4 b) {
    return (a.x != 0.f) + (a.y != 0.f) + (a.z != 0.f) + (a.w != 0.f)
         + (b.x != 0.f) + (b.y != 0.f) + (b.z != 0.f) + (b.w != 0.f);
}

// Kernel 1: build patches bf16 in layout pb[c][kb][n(96)][ks(32)].
// pb[((c*144+kb)*96+n)*32+ks] = bf16(patches[c][n][m=kb*32+ks]),
// patches[c, n=ki*9+kj, m=bi*576+bj] = x4[c, bi*9+ki, bj*9+kj].
__global__ __launch_bounds__(256) void build_pb_kernel(
    const float* __restrict__ x, uint16_t* __restrict__ pb)
{
    __shared__ float xs[PSZ][288];
    const int blk = blockIdx.x;            // 0..575
    const int c   = blk / NKB;
    const int kb  = blk - c * NKB;
    const int bi  = kb / 18;
    const int bj0 = (kb - bi * 18) * KBLK;

    const float* src = x + (size_t)(c * HPdim + bi * PSZ) * WPdim + bj0 * PSZ;
    for (int idx = threadIdx.x; idx < PSZ * 288; idx += 256) {
        int r = idx / 288, col = idx - r * 288;
        xs[r][col] = src[(size_t)r * WPdim + col];
    }
    __syncthreads();

    uint16_t* dst = pb + (size_t)(c * NKB + kb) * BCH;
    for (int oidx = threadIdx.x; oidx < BCH; oidx += 256) {
        int n = oidx / KBLK, ks = oidx - n * KBLK;
        uint16_t v = 0;
        if (n < NVALID) {
            int ki = n / PSZ, kj = n - ki * PSZ;
            v = f2bf(xs[ki][ks * PSZ + kj]);
        }
        dst[oidx] = v;
    }
}

// Kernel 2 (v6 = v4 restored, the measured-best structure @493 us):
// one block per 32(l) x 96(n) tile; 4 waves K-split (1152 each).
// Two 16-row accumulator sets share every B fragment (B-side L2 traffic
// 0.5 GB). Grid = 576 blocks. 64-row variant (v5) measured WORSE (509):
// VGPR ~230 -> 8 waves/CU occupancy tier + 288-block tail imbalance beat
// the B-traffic saving. Do not re-raise tile size.
//  - XCD-pinned channel mapping (blk&7 -> XCD; one channel per XCD-pair).
//  - register ping-pong double-buffer, peeled final iteration.
__global__ __launch_bounds__(256) void cross_gemm_kernel(
    const float* __restrict__ x,
    const float* __restrict__ attn,
    const uint16_t* __restrict__ pb,
    float* __restrict__ out)
{
    __shared__ float red[KSPLIT - 1][64][51];
    __shared__ int   cshared[KSPLIT][2][16];

    const int lane = threadIdx.x & 63;
    const int widx = threadIdx.x >> 6;
    const int blk  = blockIdx.x;              // 0..575
    // XCD-pinned decomposition: 576 = 8 slots x 72
    const int slot = blk & 7;                 // measured HW round-robin -> XCD id
    const int ii   = blk >> 3;                // 0..71
    const int c    = slot >> 1;               // one channel per XCD-pair
    const int tile = (slot & 1) * 72 + ii;    // 0..143 (32-row tiles)
    const int r0   = tile * 32;
    const int li   = lane & 15;
    const int quad = lane >> 4;
    const int k0   = widx * KSEG;
    const int kb0  = k0 / KBLK;               // widx*36

    const float* ap0 = attn + (size_t)(c * LROWS + r0 + li) * LROWS + k0 + quad * 8;
    const float* ap1 = ap0 + (size_t)16 * LROWS;
    const uint16_t* bp = pb + (size_t)(c * NKB + kb0) * BCH + li * KBLK + quad * 8;

    f32x4 acc0[6], acc1[6];
#pragma unroll
    for (int t = 0; t < 6; ++t) {
        acc0[t] = (f32x4){0.f, 0.f, 0.f, 0.f};
        acc1[t] = (f32x4){0.f, 0.f, 0.f, 0.f};
    }

    int cnt0 = 0, cnt1 = 0;
    const int DITERS = KSEG / 64;   // 18

    // preload set0 (k = 0): two row-halves
    float4 a000 = *(const float4*)(ap0);
    float4 a001 = *(const float4*)(ap0 + 4);
    float4 a010 = *(const float4*)(ap1);
    float4 a011 = *(const float4*)(ap1 + 4);
    s16x8 b0[6];
#pragma unroll
    for (int t = 0; t < 6; ++t) b0[t] = *(const s16x8*)(bp + t * 16 * KBLK);

    for (int dit = 0; dit < DITERS - 1; ++dit) {
        // issue set1 loads (k = 64*dit + 32) -- always in-segment
        float4 a100 = *(const float4*)(ap0 + 32);
        float4 a101 = *(const float4*)(ap0 + 36);
        float4 a110 = *(const float4*)(ap1 + 32);
        float4 a111 = *(const float4*)(ap1 + 36);
        s16x8 b1[6];
#pragma unroll
        for (int t = 0; t < 6; ++t) b1[t] = *(const s16x8*)(bp + BCH + t * 16 * KBLK);

        // compute set0 (both halves share b0)
        cnt0 += count8(a000, a001);
        cnt1 += count8(a010, a011);
        {
            s16x8 af0 = cvt8(a000, a001);
            s16x8 af1 = cvt8(a010, a011);
#pragma unroll
            for (int t = 0; t < 6; ++t) {
                acc0[t] = __builtin_amdgcn_mfma_f32_16x16x32_bf16(af0, b0[t], acc0[t], 0, 0, 0);
                acc1[t] = __builtin_amdgcn_mfma_f32_16x16x32_bf16(af1, b0[t], acc1[t], 0, 0, 0);
            }
        }

        // advance; issue set0 loads for next trip
        ap0 += 64;
        ap1 += 64;
        bp  += 2 * BCH;
        a000 = *(const float4*)(ap0);
        a001 = *(const float4*)(ap0 + 4);
        a010 = *(const float4*)(ap1);
        a011 = *(const float4*)(ap1 + 4);
#pragma unroll
        for (int t = 0; t < 6; ++t) b0[t] = *(const s16x8*)(bp + t * 16 * KBLK);

        // compute set1
        cnt0 += count8(a100, a101);
        cnt1 += count8(a110, a111);
        {
            s16x8 af0 = cvt8(a100, a101);
            s16x8 af1 = cvt8(a110, a111);
#pragma unroll
            for (int t = 0; t < 6; ++t) {
                acc0[t] = __builtin_amdgcn_mfma_f32_16x16x32_bf16(af0, b1[t], acc0[t], 0, 0, 0);
                acc1[t] = __builtin_amdgcn_mfma_f32_16x16x32_bf16(af1, b1[t], acc1[t], 0, 0, 0);
            }
        }
    }

    // peeled final iteration (no next-trip loads)
    {
        float4 a100 = *(const float4*)(ap0 + 32);
        float4 a101 = *(const float4*)(ap0 + 36);
        float4 a110 = *(const float4*)(ap1 + 32);
        float4 a111 = *(const float4*)(ap1 + 36);
        s16x8 b1[6];
#pragma unroll
        for (int t = 0; t < 6; ++t) b1[t] = *(const s16x8*)(bp + BCH + t * 16 * KBLK);

        cnt0 += count8(a000, a001);
        cnt1 += count8(a010, a011);
        {
            s16x8 af0 = cvt8(a000, a001);
            s16x8 af1 = cvt8(a010, a011);
#pragma unroll
            for (int t = 0; t < 6; ++t) {
                acc0[t] = __builtin_amdgcn_mfma_f32_16x16x32_bf16(af0, b0[t], acc0[t], 0, 0, 0);
                acc1[t] = __builtin_amdgcn_mfma_f32_16x16x32_bf16(af1, b0[t], acc1[t], 0, 0, 0);
            }
        }
        cnt0 += count8(a100, a101);
        cnt1 += count8(a110, a111);
        {
            s16x8 af0 = cvt8(a100, a101);
            s16x8 af1 = cvt8(a110, a111);
#pragma unroll
            for (int t = 0; t < 6; ++t) {
                acc0[t] = __builtin_amdgcn_mfma_f32_16x16x32_bf16(af0, b1[t], acc0[t], 0, 0, 0);
                acc1[t] = __builtin_amdgcn_mfma_f32_16x16x32_bf16(af1, b1[t], acc1[t], 0, 0, 0);
            }
        }
    }

    // Per-wave nonzero reduction (per half): row partials in lanes i,i+16,i+32,i+48
    cnt0 += __shfl_down(cnt0, 32);
    cnt0 += __shfl_down(cnt0, 16);
    cnt1 += __shfl_down(cnt1, 32);
    cnt1 += __shfl_down(cnt1, 16);
    if (lane < 16) {
        cshared[widx][0][lane] = cnt0;
        cshared[widx][1][lane] = cnt1;
    }

    if (widx > 0) {
#pragma unroll
        for (int t = 0; t < 6; ++t)
#pragma unroll
            for (int r = 0; r < 4; ++r) {
                red[widx - 1][lane][t * 4 + r]      = acc0[t][r];
                red[widx - 1][lane][24 + t * 4 + r] = acc1[t][r];
            }
    }
    __syncthreads();

    if (widx == 0) {
        // Epilogue: C/D layout col = lane&15 (n), row = quad*4 + reg (l)
#pragma unroll
        for (int half = 0; half < 2; ++half) {
#pragma unroll
            for (int reg = 0; reg < 4; ++reg) {
                const int lrow = quad * 4 + reg;
                const int cnt_r = cshared[0][half][lrow] + cshared[1][half][lrow]
                                + cshared[2][half][lrow] + cshared[3][half][lrow];
                const float scale = 1.0f / ((float)cnt_r + 1e-5f);
                const int l  = r0 + half * 16 + lrow;
                const int bi = l / NWp;
                const int bj = l - bi * NWp;
#pragma unroll
                for (int t = 0; t < 6; ++t) {
                    const int n = t * 16 + li;
                    if (n < NVALID) {
                        const float a = half ? acc1[t][reg] : acc0[t][reg];
                        const int ro = half * 24 + t * 4 + reg;
                        const float v = a
                                      + red[0][lane][ro]
                                      + red[1][lane][ro]
                                      + red[2][lane][ro];
                        const int ki = n / PSZ, kj = n - (n / PSZ) * PSZ;
                        const size_t idx = (size_t)(c * HPdim + bi * PSZ + ki) * WPdim
                                         + (size_t)(bj * PSZ + kj);
                        const float xv = x[idx];
                        const float o  = xv * (1.0f + v * scale);
                        out[idx] = (o > 0.f) ? o : 0.2f * o;
                    }
                }
            }
        }
    }
}

extern "C" void kernel_launch(void* const* d_in, const int* in_sizes, int n_in,
                              void* d_out, int out_size, void* d_ws, size_t ws_size,
                              hipStream_t stream)
{
    const float* x    = (const float*)d_in[0];
    const float* attn = (const float*)d_in[1];
    float* out        = (float*)d_out;
    uint16_t* pb      = (uint16_t*)d_ws;   // CH*NKB*BCH bf16 = 3.5 MB

    build_pb_kernel<<<CH * NKB, 256, 0, stream>>>(x, pb);
    cross_gemm_kernel<<<CH * 144, 256, 0, stream>>>(x, attn, pb, out);
}